// Round 32
// baseline (365.445 us; speedup 1.0000x reference)
//
#include <hip/hip_runtime.h>
#include <hip/hip_bf16.h>
#include <cstdint>
#include <cstddef>

// SimpleModuleNet MoE CNN forward — bf16 MFMA implicit-GEMM version.
// B=128, C=128, E=16, H=W=64, PROJ=512, FC=1024, NANS=2
//
// MFMA v_mfma_f32_32x32x16_bf16; A,B fragments use the SAME slot convention
// k = (lane>>5)*8 + j => any k-permutation cancels. C/D layout (HW-verified):
// col = lane&31, row = (r&3)+8*(r>>2)+4*(lane>>5).
//
// Ledger: wins = frag weights+TLP(R10), stem2 reshape(R14), prep fuse(R20),
// prep||stem1(R23), prep contiguous re-block(R25, 354.4us). Falsified/parked:
// ic-split, 1A:2ds, big-unroll stem2, fc1 {wide-N, narrow-N, ks=64, reg-dbuf,
// W->bf16 convert} (fc1 structurally parked at ~74us), stem1 oc8.
// This round: stem1 -> MFMA im2col (K=27 pad 32, 2 k-steps). stem1 was the
// last scalar-VALU conv (~55us of prep_stem1's ~75, MfmaUtil 0, VALU 45%).

typedef __bf16 bf16_t;
typedef __attribute__((ext_vector_type(4))) bf16_t bf16x4;
typedef __attribute__((ext_vector_type(8))) bf16_t bf16x8;
typedef __attribute__((ext_vector_type(16))) float f32x16;
typedef __attribute__((ext_vector_type(4))) float f32x4;

// ---------------------------------------------------------------------------
// Fused weight-prep + stem1(MFMA).
// blocks [0,128): exp_w1   [128,256): exp_w2   [256,264): stem_w2
// blocks [264,328): proj   [328,8520): stem1 MFMA (128 b x 64 tiles of 4x16)
__global__ __launch_bounds__(256) void prep_stem1_k(
    const float* __restrict__ exp_w1, const float* __restrict__ exp_w2,
    const float* __restrict__ stem_w2, const float* __restrict__ proj_w,
    bf16_t* __restrict__ wT1, bf16_t* __restrict__ wT2,
    bf16_t* __restrict__ wTs2, bf16_t* __restrict__ pwT,
    const float* __restrict__ img, const float* __restrict__ w1,
    const float* __restrict__ b1, bf16_t* __restrict__ s1out)
{
  alignas(16) __shared__ char smem[37120];   // union: prep sW[16][580] f32 /
                                             // stem1 sImg(1296B)+sCol(4096B)
  int bid = blockIdx.x;
  const int tid = threadIdx.x;

  if (bid >= 328) {
    // ---- stem1 MFMA branch: conv3x3 (3->128) + relu + maxpool2 -> NHWC ----
    // im2col: K = ic*9 + dy*3 + dx (27 valid, pad to 32; zero-pad cancels
    // because A and B both zero k>=27 and share the k-slot convention).
    bid -= 328;                            // 128 b * 64 tiles
    const int b  = bid >> 6;
    const int t  = bid & 63;
    const int ty = t >> 2, tx = t & 3;     // tile = 4 conv rows x 16 cols
    const int y0 = ty * 4, x0 = tx * 16;
    const int lane = tid & 63, wv = tid >> 6;
    const int g = lane >> 5, p = lane & 31;

    float*  sImg = (float*)smem;           // [3][6][18] f32 (ic*108+rr*18+cc)
    bf16_t* sCol = (bf16_t*)(smem + 1296); // [64 px][32 k] bf16

    // stage image tile: rows y0-1..y0+4 (6), cols x0-1..x0+16 (18), 3 ch
    for (int s2 = tid; s2 < 324; s2 += 256) {
      const int ic = s2 / 108, r2 = s2 - ic * 108;
      const int rr = r2 / 18, cc2 = r2 - rr * 18;
      const int gy = y0 - 1 + rr, gx = x0 - 1 + cc2;
      float v = 0.f;
      if (gy >= 0 && gy < 64 && gx >= 0 && gx < 64)
        v = img[(((size_t)b * 3 + ic) * 64 + gy) * 64 + gx];
      sImg[ic * 108 + rr * 18 + cc2] = v;
    }

    // A-frags from w1 (L1-resident 13.8KB); independent of LDS -> load early.
    // wave (wv&1) owns og pair; row oc = og*32 + p; k = s*16 + g*8 + j.
    bf16x8 a0[2], a1[2];
#pragma unroll
    for (int ogi = 0; ogi < 2; ++ogi) {
      const int og = (wv & 1) * 2 + ogi;
      const float* wrow = w1 + (size_t)(og * 32 + p) * 27;
#pragma unroll
      for (int j = 0; j < 8; ++j) {
        a0[ogi][j] = (bf16_t)wrow[g * 8 + j];          // k = 0..15 (<27)
        const int k1 = 16 + g * 8 + j;
        a1[ogi][j] = (k1 < 27) ? (bf16_t)wrow[k1] : (bf16_t)0.f;
      }
    }
    __syncthreads();

    // build im2col [tp][k]: k = tid&31 (loop-invariant), tp = tid>>5 + i*8
    {
      const int k = tid & 31;
      const int tpb = tid >> 5;
      const bool kv = k < 27;
      const int ic = k / 9, rem = k - ic * 9;
      const int dy = rem / 3, dx = rem - dy * 3;
#pragma unroll
      for (int i = 0; i < 8; ++i) {
        const int tp = tpb + i * 8;
        const int py = tp >> 4, px = tp & 15;
        const float v = kv ? sImg[ic * 108 + (py + dy) * 18 + px + dx] : 0.f;
        sCol[tp * 32 + k] = (bf16_t)v;
      }
    }
    __syncthreads();

    // B-frags: wave strip = rows 2*(wv>>1), +1; tp = (wv>>1)*32 + p
    const int tp = (wv >> 1) * 32 + p;
    const bf16x8 bfr0 = *(const bf16x8*)(sCol + tp * 32 + g * 8);
    const bf16x8 bfr1 = *(const bf16x8*)(sCol + tp * 32 + 16 + g * 8);

    f32x16 acc[2];
#pragma unroll
    for (int i = 0; i < 2; ++i)
#pragma unroll
      for (int r = 0; r < 16; ++r) acc[i][r] = 0.f;

#pragma unroll
    for (int ogi = 0; ogi < 2; ++ogi) {
      acc[ogi] = __builtin_amdgcn_mfma_f32_32x32x16_bf16(a0[ogi], bfr0, acc[ogi], 0, 0, 0);
      acc[ogi] = __builtin_amdgcn_mfma_f32_32x32x16_bf16(a1[ogi], bfr1, acc[ogi], 0, 0, 0);
    }

    // epilogue: 2x2 pool (shfl_xor 1,16) + bias + relu -> NHWC bf16
    const int gpy = ty * 2 + (wv >> 1);          // pooled row 0..31
    const int gpx = tx * 8 + (p >> 1);           // pooled col
    const bool wr = (p & 17) == 0;
    bf16_t* op = s1out + ((size_t)(b * 1024 + gpy * 32 + gpx)) * 128;
#pragma unroll
    for (int ogi = 0; ogi < 2; ++ogi) {
      const int og = (wv & 1) * 2 + ogi;
#pragma unroll
      for (int rq = 0; rq < 4; ++rq) {
        const int oc4 = og * 32 + rq * 8 + g * 4;
        const f32x4 bi = *(const f32x4*)(b1 + oc4);
        bf16x4 qv;
#pragma unroll
        for (int j = 0; j < 4; ++j) {
          float v = acc[ogi][rq * 4 + j];
          v = fmaxf(v, __shfl_xor(v, 1));
          v = fmaxf(v, __shfl_xor(v, 16));
          qv[j] = (bf16_t)fmaxf(v + bi[j], 0.f);
        }
        if (wr) *(bf16x4*)(op + oc4) = qv;
      }
    }
    return;
  }

  if (bid >= 264) {
    // ---- proj branch: [512 oc][128 ic] fp32 -> fragment order ----
    const int base = (bid - 264) * 1024 + tid;
#pragma unroll
    for (int it = 0; it < 4; ++it) {
      const int idx = base + it * 256;     // 0..65535 = oc*128 + ic
      const int oc = idx >> 7, ic = idx & 127;
      const int og = oc >> 5, cc2 = oc & 31;
      const int ich2 = ic >> 6, icl = ic & 63;
      const int kh2 = icl >> 4, g2 = (icl >> 3) & 1, j2 = icl & 7;
      const int off = ((((og * 2 + ich2) * 4 + kh2) << 9)) + ((g2 << 5) + cc2) * 8 + j2;
      pwT[off] = (bf16_t)proj_w[(size_t)oc * 128 + ic];
    }
    return;
  }

  // ---- conv weight prep: block = (e,ocg,ich); CONTIGUOUS reads via LDS ----
  const float* in;
  bf16_t* out;
  if (bid < 128)      { in = exp_w1;  out = wT1; }
  else if (bid < 256) { in = exp_w2;  out = wT2;  bid -= 128; }
  else                { in = stem_w2; out = wTs2; bid -= 256; }   // e=0 only
  const int e   = bid >> 3;
  const int rem = bid & 7;
  const int ocg = rem >> 1, ich = rem & 1;

  float* sW = (float*)smem;                // [16][580] floats (row stride 580)
  bf16_t* outb = out + (size_t)e * 147456;

  for (int h = 0; h < 2; ++h) {
    if (h) __syncthreads();                // previous half's readers done
    for (int idx = tid; idx < 2304; idx += 256) {
      const int r16 = idx / 144, q = idx - r16 * 144;
      const float* src = in + (size_t)(e * 128 + ocg * 32 + h * 16 + r16) * 1152
                       + ich * 576 + q * 4;
      *(f32x4*)(&sW[r16 * 580 + q * 4]) = *(const f32x4*)src;
    }
    __syncthreads();
    for (int c = tid; c < 1152; c += 256) {
      const int dd  = c >> 7;
      const int kh  = (c >> 5) & 3;
      const int g2  = (c >> 4) & 1;
      const int c16 = c & 15;
      const int cc  = h * 16 + c16;
      bf16x8 v;
#pragma unroll
      for (int j = 0; j < 8; ++j)
        v[j] = (bf16_t)sW[c16 * 580 + (kh * 16 + g2 * 8 + j) * 9 + dd];
      bf16_t* op = outb + ((size_t)(((ocg * 2 + ich) * 9 + dd) * 4 + kh) << 9)
                 + (g2 * 32 + cc) * 8;
      *(bf16x8*)op = v;
    }
  }
}

// ---------------------------------------------------------------------------
// stem2: conv3x3 128->128 on 32x32 NHWC bf16 + relu + maxpool2 -> 16x16 NHWC.
__global__ __launch_bounds__(256) void conv_stem2_k(
    const bf16_t* __restrict__ act, const bf16_t* __restrict__ wF,
    const float* __restrict__ bias, bf16_t* __restrict__ out)
{
  const int b = blockIdx.x >> 4, ph = blockIdx.x & 15;
  const int y0 = ph * 2;                 // conv rows y0, y0+1
  const int tid = threadIdx.x, lane = tid & 63, wv = tid >> 6;
  const int g = lane >> 5, cc = lane & 31;
  const int wq = wv;                     // 0..3: which 32-oc fragment

  __shared__ bf16_t simg[272 * 64];      // [ich2][4 rows][34 cols][64ch], 34 KB swz

  f32x16 acc[2];
#pragma unroll
  for (int i = 0; i < 2; ++i)
#pragma unroll
    for (int r = 0; r < 16; ++r) acc[i][r] = 0.f;

  const bf16_t* wfb = wF + ((size_t)(wq * 2) * 9 * 4 << 9) + lane * 8;

  // stage rows y0-1..y0+2 (4), cols -1..32 (34), both ic-halves, swizzled
  for (int p = tid; p < 272; p += 256) {
    const int ich = p / 136, r2 = p - ich * 136;
    const int yy = r2 / 34, xx = r2 - yy * 34;
    const int gy = y0 + yy - 1, gx = xx - 1;
    const bool inb = (gy >= 0 && gy < 32 && gx >= 0 && gx < 32);
    const bf16_t* src = act + ((size_t)(b * 1024 + gy * 32 + gx)) * 128 + ich * 64;
#pragma unroll
    for (int j = 0; j < 8; ++j) {
      bf16x8 v = {};
      if (inb) v = *(const bf16x8*)(src + j * 8);
      const int waddr = (p * 128 + j * 16) ^ ((p & 7) << 4);
      *(bf16x8*)((char*)simg + waddr) = v;
    }
  }
  __syncthreads();

#pragma unroll
  for (int ich = 0; ich < 2; ++ich) {
#pragma unroll
    for (int dydx = 0; dydx < 9; ++dydx) {
      const int dy = dydx / 3, dx = dydx - dy * 3;
      const bf16_t* wf = wfb + (((ich * 9 + dydx) * 4) << 9);
#pragma unroll
      for (int kh = 0; kh < 4; ++kh) {
        const bf16x8 a = *(const bf16x8*)(wf + (kh << 9));
#pragma unroll
        for (int r = 0; r < 2; ++r) {
          const int s = ich * 136 + (r + dy) * 34 + cc + dx;
          const int raddr = (s * 128 + (kh * 2 + g) * 16) ^ ((s & 7) << 4);
          const bf16x8 bbv = *(const bf16x8*)((const char*)simg + raddr);
          acc[r] = __builtin_amdgcn_mfma_f32_32x32x16_bf16(a, bbv, acc[r], 0, 0, 0);
        }
      }
    }
  }

  // epilogue: bias -> 2x2 pool -> relu -> NHWC bf16 (pooled row = ph)
  const int pxp = cc >> 1;
  bf16_t* op = out + ((size_t)(b * 256 + ph * 16 + pxp)) * 128;
#pragma unroll
  for (int rq = 0; rq < 4; ++rq) {
    const int oc4 = wq * 32 + rq * 8 + g * 4;
    const f32x4 bi = *(const f32x4*)(bias + oc4);
    bf16x4 qv;
#pragma unroll
    for (int j = 0; j < 4; ++j) {
      const int r = rq * 4 + j;
      float v = fmaxf(acc[0][r], acc[1][r]);
      v = fmaxf(v, __shfl_xor(v, 1));
      qv[j] = (bf16_t)fmaxf(v + bi[j], 0.f);
    }
    if ((cc & 1) == 0) *(bf16x4*)(op + oc4) = qv;
  }
}

// ---------------------------------------------------------------------------
// Expert conv3x3 128->128 on 16x16 NHWC — R14-EXACT measured-best body.
template<int RES>
__global__ __launch_bounds__(256) void conv_exp_k(
    const bf16_t* __restrict__ act, const bf16_t* __restrict__ wF,
    const float* __restrict__ bias, const int* __restrict__ question, int col,
    const bf16_t* __restrict__ res, bf16_t* __restrict__ out)
{
  const int b = blockIdx.x >> 2, ph = blockIdx.x & 3;
  const int y0 = ph * 4;
  const int e = question[b * 8 + col];
  const int tid = threadIdx.x, lane = tid & 63, wv = tid >> 6;
  const int g = lane >> 5, cc = lane & 31;
  const int wq_oc = wv & 1, wq_px = wv >> 1;

  __shared__ bf16_t simg[216 * 64];      // [ich2][6 rows][18 cols][64ch], 27 KB

  f32x16 acc[2];
#pragma unroll
  for (int i = 0; i < 2; ++i)
#pragma unroll
    for (int r = 0; r < 16; ++r) acc[i][r] = 0.f;

  const int px = wq_px * 32 + cc;        // 0..63 within 4x16 strip
  const int sl = (px >> 4) * 18 + (px & 15);

  const bf16_t* wfb = wF + (size_t)e * 147456
                    + (((size_t)(wq_oc * 2) * 2) * 9 * 4 << 9) + lane * 8;

  // stage rows y0-1..y0+4 (6), cols -1..16 (18), both ic-halves, swizzled
  for (int p = tid; p < 216; p += 256) {
    const int ich = p / 108, r2 = p - ich * 108;
    const int yy = r2 / 18, xx = r2 - yy * 18;
    const int gy = y0 + yy - 1, gx = xx - 1;
    const bool inb = (gy >= 0 && gy < 16 && gx >= 0 && gx < 16);
    const bf16_t* src = act + ((size_t)(b * 256 + gy * 16 + gx)) * 128 + ich * 64;
#pragma unroll
    for (int j = 0; j < 8; ++j) {
      bf16x8 v = {};
      if (inb) v = *(const bf16x8*)(src + j * 8);
      const int waddr = (p * 128 + j * 16) ^ ((p & 7) << 4);
      *(bf16x8*)((char*)simg + waddr) = v;
    }
  }
  __syncthreads();

#pragma unroll
  for (int ich = 0; ich < 2; ++ich) {
#pragma unroll
    for (int dydx = 0; dydx < 9; ++dydx) {
      const int dy = dydx / 3, dx = dydx - dy * 3;
      const int sbase = ich * 108 + sl + dy * 18 + dx;
      const bf16_t* wf = wfb + (((ich * 9 + dydx) * 4) << 9);
#pragma unroll
      for (int kh = 0; kh < 4; ++kh) {
        const bf16x8 a0 = *(const bf16x8*)(wf + (kh << 9));
        const bf16x8 a1 = *(const bf16x8*)(wf + 36864 + (kh << 9));
        const int raddr = (sbase * 128 + (kh * 2 + g) * 16) ^ ((sbase & 7) << 4);
        const bf16x8 bbv = *(const bf16x8*)((const char*)simg + raddr);
        acc[0] = __builtin_amdgcn_mfma_f32_32x32x16_bf16(a0, bbv, acc[0], 0, 0, 0);
        acc[1] = __builtin_amdgcn_mfma_f32_32x32x16_bf16(a1, bbv, acc[1], 0, 0, 0);
      }
    }
  }

  const float* bb = bias + e * 128;
  const size_t pixbase = ((size_t)(b * 256 + (y0 + (px >> 4)) * 16 + (px & 15))) * 128;
  bf16_t* op = out + pixbase;
#pragma unroll
  for (int mf = 0; mf < 2; ++mf) {
#pragma unroll
    for (int rq = 0; rq < 4; ++rq) {
      const int oc4 = wq_oc * 64 + mf * 32 + rq * 8 + g * 4;
      const f32x4 bi = *(const f32x4*)(bb + oc4);
      bf16x4 qv;
      bf16x4 rv = {};
      if (RES) rv = *(const bf16x4*)(res + pixbase + oc4);
#pragma unroll
      for (int j = 0; j < 4; ++j) {
        float v = acc[mf][rq * 4 + j] + bi[j];
        if (RES) v += (float)rv[j];
        qv[j] = (bf16_t)fmaxf(v, 0.f);
      }
      *(bf16x4*)(op + oc4) = qv;
    }
  }
}

// ---------------------------------------------------------------------------
// proj 1x1 conv 128->512 + relu + maxpool2, NHWC bf16 in -> f bf16 NCHW
// (128,512,8,8). Fragment weights.
__global__ __launch_bounds__(256) void proj_mfma_k(
    const bf16_t* __restrict__ h, const bf16_t* __restrict__ pwF,
    const float* __restrict__ pb, bf16_t* __restrict__ f)
{
  const int b = blockIdx.x >> 2, ocg = blockIdx.x & 3;
  const int tid = threadIdx.x, lane = tid & 63, wv = tid >> 6;
  const int g = lane >> 5, cc = lane & 31;
  const int wq_oc = wv & 1, wq_px = wv >> 1;

  __shared__ bf16_t simg[256 * 64];

  f32x16 acc[2][4];
#pragma unroll
  for (int i = 0; i < 2; ++i)
#pragma unroll
    for (int j = 0; j < 4; ++j)
#pragma unroll
      for (int r = 0; r < 16; ++r) acc[i][j][r] = 0.f;

  const int px0 = wq_px * 128 + cc;
  const int og0 = ocg * 4 + wq_oc * 2;
  const bf16_t* pfb = pwF + (((size_t)og0 * 2 * 4) << 9) + lane * 8;

  for (int ich = 0; ich < 2; ++ich) {
    __syncthreads();
    {
      const int p = tid;
      const bf16_t* src = h + ((size_t)(b * 256 + p)) * 128 + ich * 64;
#pragma unroll
      for (int j = 0; j < 8; ++j) {
        bf16x8 v = *(const bf16x8*)(src + j * 8);
        const int waddr = (p * 128 + j * 16) ^ ((p & 7) << 4);
        *(bf16x8*)((char*)simg + waddr) = v;
      }
    }
    __syncthreads();

#pragma unroll
    for (int kh = 0; kh < 4; ++kh) {
      const bf16x8 a0 = *(const bf16x8*)(pfb + ((ich * 4 + kh) << 9));
      const bf16x8 a1 = *(const bf16x8*)(pfb + 4096 + ((ich * 4 + kh) << 9));
#pragma unroll
      for (int nf = 0; nf < 4; ++nf) {
        const int s = px0 + nf * 32;
        const int raddr = (s * 128 + (kh * 2 + g) * 16) ^ ((s & 7) << 4);
        const bf16x8 bb = *(const bf16x8*)((const char*)simg + raddr);
        acc[0][nf] = __builtin_amdgcn_mfma_f32_32x32x16_bf16(a0, bb, acc[0][nf], 0, 0, 0);
        acc[1][nf] = __builtin_amdgcn_mfma_f32_32x32x16_bf16(a1, bb, acc[1][nf], 0, 0, 0);
      }
    }
  }

#pragma unroll
  for (int mf = 0; mf < 2; ++mf) {
#pragma unroll
    for (int nf = 0; nf < 4; ++nf) {
      const int px = px0 + nf * 32;
      const int x = px & 15;
      const int py = wq_px * 4 + nf;
      const int pxp = x >> 1;
#pragma unroll
      for (int r = 0; r < 16; ++r) {
        float v = acc[mf][nf][r];
        v = fmaxf(v, __shfl_xor(v, 1));
        v = fmaxf(v, __shfl_xor(v, 16));
        const int oc = ocg * 128 + wq_oc * 64 + mf * 32 + (r & 3) + 8 * (r >> 2) + 4 * g;
        v = fmaxf(v + pb[oc], 0.f);
        if ((cc & 17) == 0)
          f[((size_t)(b * 512 + oc)) * 64 + py * 8 + pxp] = (bf16_t)v;
      }
    }
  }
}

// ---------------------------------------------------------------------------
// fc1 as bf16 MFMA GEMM (R25 measured-best config):
// grid = (16 n-tiles of 64) x (32 k-slices of 1024); 256 thr = 4 waves (2m x 2n).
__global__ __launch_bounds__(256) void fc1_mfma_k(
    const bf16_t* __restrict__ A, const float* __restrict__ W,
    float* __restrict__ part)
{
  const int nt = blockIdx.x;        // 0..15
  const int ks = blockIdx.y;        // 0..31
  const int n0 = nt * 64;
  const int k0 = ks * 1024;
  const int tid = threadIdx.x, lane = tid & 63, wv = tid >> 6;
  const int g = lane >> 5, cc = lane & 31;
  const int mh = wv & 1, nh = wv >> 1;

  __shared__ char sA[16384];   // [128][64] bf16, XOR-swizzled
  __shared__ char sB[8192];    // [64][64] bf16, XOR-swizzled

  f32x16 acc0, acc1;
#pragma unroll
  for (int r = 0; r < 16; ++r) { acc0[r] = 0.f; acc1[r] = 0.f; }

  for (int t = 0; t < 16; ++t) {   // 16 K-tiles of 64
    __syncthreads();
#pragma unroll
    for (int i = 0; i < 4; ++i) {
      const int c = tid + i * 256;
      const int row = c >> 3, ko = c & 7;
      bf16x8 v = *(const bf16x8*)(A + (size_t)row * 32768 + k0 + t * 64 + ko * 8);
      const int wa = (row * 128 + ko * 16) ^ ((row & 7) << 4);
      *(bf16x8*)(sA + wa) = v;
    }
#pragma unroll
    for (int i = 0; i < 2; ++i) {
      const int c = tid + i * 256;
      const int row = c >> 3, ko = c & 7;
      const float* src = W + (size_t)(n0 + row) * 32768 + k0 + t * 64 + ko * 8;
      f32x4 u0 = *(const f32x4*)src;
      f32x4 u1 = *(const f32x4*)(src + 4);
      bf16x8 v;
#pragma unroll
      for (int j = 0; j < 4; ++j) { v[j] = (bf16_t)u0[j]; v[4 + j] = (bf16_t)u1[j]; }
      const int wa = (row * 128 + ko * 16) ^ ((row & 7) << 4);
      *(bf16x8*)(sB + wa) = v;
    }
    __syncthreads();
#pragma unroll
    for (int kss = 0; kss < 4; ++kss) {
      const int kb = kss * 32 + g * 16;
      const int rA0 = mh * 64 + cc, rA1 = rA0 + 32;
      const bf16x8 a0 = *(const bf16x8*)(sA + ((rA0 * 128 + kb) ^ ((rA0 & 7) << 4)));
      const bf16x8 a1 = *(const bf16x8*)(sA + ((rA1 * 128 + kb) ^ ((rA1 & 7) << 4)));
      const int rB = nh * 32 + cc;
      const bf16x8 bb = *(const bf16x8*)(sB + ((rB * 128 + kb) ^ ((rB & 7) << 4)));
      acc0 = __builtin_amdgcn_mfma_f32_32x32x16_bf16(a0, bb, acc0, 0, 0, 0);
      acc1 = __builtin_amdgcn_mfma_f32_32x32x16_bf16(a1, bb, acc1, 0, 0, 0);
    }
  }

  float* pp = part + ((size_t)ks * 128) * 1024 + n0 + nh * 32 + cc;
#pragma unroll
  for (int r = 0; r < 16; ++r) {
    const int m0 = mh * 64 + (r & 3) + 8 * (r >> 2) + 4 * g;
    pp[(size_t)m0 * 1024] = acc0[r];
    pp[(size_t)(m0 + 32) * 1024] = acc1[r];
  }
}

__global__ __launch_bounds__(256) void fc1_red_k(
    const float* __restrict__ part, const float* __restrict__ bias, float* __restrict__ fo)
{
  const int i = blockIdx.x * 256 + threadIdx.x;   // 131072
  const int m = i >> 10, j = i & 1023;
  float s = bias[j];
#pragma unroll
  for (int ks = 0; ks < 32; ++ks) s += part[((size_t)ks * 128 + m) * 1024 + j];
  fo[i] = fmaxf(s, 0.f);
}

// ---------------------------------------------------------------------------
__global__ __launch_bounds__(256) void fc2_k(
    const float* __restrict__ fo, const float* __restrict__ w2,
    const float* __restrict__ b2, float* __restrict__ out)
{
  const int m = blockIdx.x;
  const int tid = threadIdx.x;
  float a0 = 0.f, a1 = 0.f;
  for (int k = tid; k < 1024; k += 256) {
    const float fv = fo[(size_t)m * 1024 + k];
    a0 = fmaf(fv, w2[k], a0);
    a1 = fmaf(fv, w2[1024 + k], a1);
  }
#pragma unroll
  for (int o = 32; o > 0; o >>= 1) {
    a0 += __shfl_down(a0, o);
    a1 += __shfl_down(a1, o);
  }
  __shared__ float r0[4], r1[4];
  const int wid = tid >> 6;
  if ((tid & 63) == 0) { r0[wid] = a0; r1[wid] = a1; }
  __syncthreads();
  if (tid == 0) {
    out[(size_t)m * 2 + 0] = r0[0] + r0[1] + r0[2] + r0[3] + b2[0];
    out[(size_t)m * 2 + 1] = r1[0] + r1[1] + r1[2] + r1[3] + b2[1];
  }
}

// ---------------------------------------------------------------------------
extern "C" void kernel_launch(void* const* d_in, const int* in_sizes, int n_in,
                              void* d_out, int out_size, void* d_ws, size_t ws_size,
                              hipStream_t stream)
{
  const float* image    = (const float*)d_in[0];
  const int*   question = (const int*)  d_in[1];
  const float* stem_w1  = (const float*)d_in[2];
  const float* stem_b1  = (const float*)d_in[3];
  const float* stem_w2  = (const float*)d_in[4];
  const float* stem_b2  = (const float*)d_in[5];
  const float* exp_w1   = (const float*)d_in[6];
  const float* exp_b1   = (const float*)d_in[7];
  const float* exp_w2   = (const float*)d_in[8];
  const float* exp_b2   = (const float*)d_in[9];
  const float* proj_w   = (const float*)d_in[10];
  const float* proj_b   = (const float*)d_in[11];
  const float* fc1_w    = (const float*)d_in[12];
  const float* fc1_b    = (const float*)d_in[13];
  const float* fc2_w    = (const float*)d_in[14];
  const float* fc2_b    = (const float*)d_in[15];
  float* out = (float*)d_out;

  char* base = (char*)d_ws;
  bf16_t* actA   = (bf16_t*)(base + 33554432);         // 33,554,432 B (NHWC 32x32)
  bf16_t* actH   = (bf16_t*)(base + 67108864);         //  8,388,608 B (NHWC 16x16)
  bf16_t* actT   = (bf16_t*)(base + 75497472);         //  8,388,608 B
  bf16_t* wT1    = (bf16_t*)(base + 83886080);         //  4,718,592 B (frag)
  bf16_t* wT2    = (bf16_t*)(base + 88604672);         //  4,718,592 B (frag)
  bf16_t* wTs2   = (bf16_t*)(base + 93323264);         //    294,912 B (frag)
  bf16_t* pwT    = (bf16_t*)(base + 93618176);         //    131,072 B (frag)
  // region0 reuse: f bf16, fc1 partials (32 slices), fc1 out
  bf16_t* fbf  = (bf16_t*)base;                        //  8,388,608 B
  float*  part = (float*)(base + 8388608);             // 16,777,216 B (32x128x1024)
  float*  f1o  = (float*)(base + 25165824);            //    524,288 B

  // fused weight prep || stem1 MFMA (328 prep blocks + 8192 stem1 tiles)
  prep_stem1_k<<<8520, 256, 0, stream>>>(exp_w1, exp_w2, stem_w2, proj_w,
                                         wT1, wT2, wTs2, pwT,
                                         image, stem_w1, stem_b1, actA);

  conv_stem2_k<<<2048, 256, 0, stream>>>(actA, wTs2, stem_b2, actH);

  // expert residual blocks, routing cols (3,4,6,7,5)
  const int cols[5] = {3, 4, 6, 7, 5};
  for (int i = 0; i < 5; ++i) {
    conv_exp_k<0><<<512, 256, 0, stream>>>(actH, wT1, exp_b1, question, cols[i],
                                           nullptr, actT);
    conv_exp_k<1><<<512, 256, 0, stream>>>(actT, wT2, exp_b2, question, cols[i],
                                           actH, actH);
  }

  // head
  proj_mfma_k<<<512, 256, 0, stream>>>(actH, pwT, proj_b, fbf);
  fc1_mfma_k<<<dim3(16, 32), 256, 0, stream>>>(fbf, fc1_w, part);
  fc1_red_k<<<512, 256, 0, stream>>>(part, fc1_b, f1o);
  fc2_k<<<128, 256, 0, stream>>>(f1o, fc2_w, fc2_b, out);
}

// Round 33
// 352.401 us; speedup vs baseline: 1.0370x; 1.0370x over previous
//
#include <hip/hip_runtime.h>
#include <hip/hip_bf16.h>
#include <cstdint>
#include <cstddef>

// SimpleModuleNet MoE CNN forward — bf16 MFMA implicit-GEMM (R25-best + fused head).
// B=128, C=128, E=16, H=W=64, PROJ=512, FC=1024, NANS=2
//
// MFMA v_mfma_f32_32x32x16_bf16; A,B fragments use the SAME slot convention
// k = (lane>>5)*8 + j => any k-permutation cancels. C/D layout (HW-verified):
// col = lane&31, row = (r&3)+8*(r>>2)+4*(lane>>5).
//
// Final ledger: wins = frag weights+TLP(R10), stem2 reshape(R14), prep fuse
// (R20), prep||stem1(R23), prep contiguous re-block(R25), fused fc head (R33).
// Falsified/parked: ic-split, 1A:2ds, big-unroll stem2, stem1 oc8, stem1 MFMA
// im2col (R32: small-block overhead > pipe win at 3 input ch), fc1 {wide-N,
// narrow-N, ks=64, reg-dbuf} (structurally parked ~74us), W->bf16 convert
// anywhere (~30us cost vs ~25us save).

typedef __bf16 bf16_t;
typedef __attribute__((ext_vector_type(4))) bf16_t bf16x4;
typedef __attribute__((ext_vector_type(8))) bf16_t bf16x8;
typedef __attribute__((ext_vector_type(16))) float f32x16;
typedef __attribute__((ext_vector_type(4))) float f32x4;

// ---------------------------------------------------------------------------
// Fused weight-prep + stem1 (R25-exact).
// blocks [0,128): exp_w1   [128,256): exp_w2   [256,264): stem_w2
// blocks [264,328): proj   [328,2376): stem1
__global__ __launch_bounds__(256) void prep_stem1_k(
    const float* __restrict__ exp_w1, const float* __restrict__ exp_w2,
    const float* __restrict__ stem_w2, const float* __restrict__ proj_w,
    bf16_t* __restrict__ wT1, bf16_t* __restrict__ wT2,
    bf16_t* __restrict__ wTs2, bf16_t* __restrict__ pwT,
    const float* __restrict__ img, const float* __restrict__ w1,
    const float* __restrict__ b1, bf16_t* __restrict__ s1out)
{
  alignas(16) __shared__ char smem[37120];   // union: prep sW[16][580] f32 /
                                             // stem1 sImg(4104B)+pad+sOut(16384B)
  int bid = blockIdx.x;
  const int tid = threadIdx.x;

  if (bid >= 328) {
    // ---- stem1 branch: conv3x3 (3->128) + relu + maxpool2 -> NHWC bf16 ----
    bid -= 328;                           // 128 b * 16 tiles
    float* sImg = (float*)smem;           // [3][18][19] floats (idx ic*342+rr*19+cc)
    char*  sOut = smem + 4112;            // [64 px][128 oc] bf16, XOR-swizzled
    const int b = bid >> 4, t = bid & 15;
    const int ty0p = (t >> 2) * 8, tx0p = (t & 3) * 8;
    const int lane = tid & 63;
    const int wvbase = __builtin_amdgcn_readfirstlane(tid >> 6) * 32;

    for (int s = tid; s < 972; s += 256) {
      const int ic = s / 324, r2 = s - ic * 324;
      const int rr = r2 / 18, cc = r2 - rr * 18;
      const int gy = 2 * ty0p - 1 + rr, gx = 2 * tx0p - 1 + cc;
      float v = 0.f;
      if (gy >= 0 && gy < 64 && gx >= 0 && gx < 64)
        v = img[(((size_t)b * 3 + ic) * 64 + gy) * 64 + gx];
      sImg[ic * 342 + rr * 19 + cc] = v;
    }
    __syncthreads();

    const int ppy = lane >> 3, ppx = lane & 7;
    const int swz = (lane & 15) << 3;
    char* orow = sOut + lane * 256;

    for (int oc8 = 0; oc8 < 32; oc8 += 8) {
      float acc[8][2][2];
#pragma unroll
      for (int q = 0; q < 8; ++q) {
        const float bv = b1[wvbase + oc8 + q];
#pragma unroll
        for (int i = 0; i < 2; ++i)
#pragma unroll
          for (int jj = 0; jj < 2; ++jj) acc[q][i][jj] = bv;
      }
#pragma unroll
      for (int ic = 0; ic < 3; ++ic)
#pragma unroll
        for (int dy = 0; dy < 3; ++dy)
#pragma unroll
          for (int dx = 0; dx < 3; ++dx) {
            const float p00 = sImg[ic * 342 + (2 * ppy + dy) * 19 + 2 * ppx + dx];
            const float p01 = sImg[ic * 342 + (2 * ppy + dy) * 19 + 2 * ppx + dx + 1];
            const float p10 = sImg[ic * 342 + (2 * ppy + dy + 1) * 19 + 2 * ppx + dx];
            const float p11 = sImg[ic * 342 + (2 * ppy + dy + 1) * 19 + 2 * ppx + dx + 1];
#pragma unroll
            for (int q = 0; q < 8; ++q) {
              const float wv2 = w1[(wvbase + oc8 + q) * 27 + ic * 9 + dy * 3 + dx];
              acc[q][0][0] = fmaf(p00, wv2, acc[q][0][0]);
              acc[q][0][1] = fmaf(p01, wv2, acc[q][0][1]);
              acc[q][1][0] = fmaf(p10, wv2, acc[q][1][0]);
              acc[q][1][1] = fmaf(p11, wv2, acc[q][1][1]);
            }
          }
#pragma unroll
      for (int h4 = 0; h4 < 8; h4 += 4) {
        bf16x4 qv;
#pragma unroll
        for (int j = 0; j < 4; ++j) {
          const int q = h4 + j;
          const float mx = fmaxf(fmaxf(acc[q][0][0], acc[q][0][1]),
                                 fmaxf(acc[q][1][0], acc[q][1][1]));
          qv[j] = (bf16_t)fmaxf(mx, 0.f);
        }
        *(bf16x4*)(orow + (((wvbase + oc8 + h4) * 2) ^ swz)) = qv;
      }
    }
    __syncthreads();

#pragma unroll
    for (int it = 0; it < 4; ++it) {
      const int idx = it * 256 + tid;
      const int px = idx >> 4, ch8 = idx & 15;
      const int sw = (px & 15) << 3;
      const char* rb = sOut + px * 256;
      bf16x4 lo = *(const bf16x4*)(rb + ((ch8 * 16) ^ sw));
      bf16x4 hi = *(const bf16x4*)(rb + ((ch8 * 16 + 8) ^ sw));
      bf16x8 v;
#pragma unroll
      for (int j = 0; j < 4; ++j) { v[j] = lo[j]; v[4 + j] = hi[j]; }
      const int gpy = ty0p + (px >> 3), gpx = tx0p + (px & 7);
      *(bf16x8*)(s1out + ((size_t)(b * 1024 + gpy * 32 + gpx)) * 128 + ch8 * 8) = v;
    }
    return;
  }

  if (bid >= 264) {
    // ---- proj branch: [512 oc][128 ic] fp32 -> fragment order ----
    const int base = (bid - 264) * 1024 + tid;
#pragma unroll
    for (int it = 0; it < 4; ++it) {
      const int idx = base + it * 256;     // 0..65535 = oc*128 + ic
      const int oc = idx >> 7, ic = idx & 127;
      const int og = oc >> 5, cc2 = oc & 31;
      const int ich2 = ic >> 6, icl = ic & 63;
      const int kh2 = icl >> 4, g2 = (icl >> 3) & 1, j2 = icl & 7;
      const int off = ((((og * 2 + ich2) * 4 + kh2) << 9)) + ((g2 << 5) + cc2) * 8 + j2;
      pwT[off] = (bf16_t)proj_w[(size_t)oc * 128 + ic];
    }
    return;
  }

  // ---- conv weight prep: block = (e,ocg,ich); CONTIGUOUS reads via LDS ----
  const float* in;
  bf16_t* out;
  if (bid < 128)      { in = exp_w1;  out = wT1; }
  else if (bid < 256) { in = exp_w2;  out = wT2;  bid -= 128; }
  else                { in = stem_w2; out = wTs2; bid -= 256; }   // e=0 only
  const int e   = bid >> 3;
  const int rem = bid & 7;
  const int ocg = rem >> 1, ich = rem & 1;

  float* sW = (float*)smem;                // [16][580] floats (row stride 580)
  bf16_t* outb = out + (size_t)e * 147456;

  for (int h = 0; h < 2; ++h) {
    if (h) __syncthreads();                // previous half's readers done
    for (int idx = tid; idx < 2304; idx += 256) {
      const int r16 = idx / 144, q = idx - r16 * 144;
      const float* src = in + (size_t)(e * 128 + ocg * 32 + h * 16 + r16) * 1152
                       + ich * 576 + q * 4;
      *(f32x4*)(&sW[r16 * 580 + q * 4]) = *(const f32x4*)src;
    }
    __syncthreads();
    for (int c = tid; c < 1152; c += 256) {
      const int dd  = c >> 7;
      const int kh  = (c >> 5) & 3;
      const int g2  = (c >> 4) & 1;
      const int c16 = c & 15;
      const int cc  = h * 16 + c16;
      bf16x8 v;
#pragma unroll
      for (int j = 0; j < 8; ++j)
        v[j] = (bf16_t)sW[c16 * 580 + (kh * 16 + g2 * 8 + j) * 9 + dd];
      bf16_t* op = outb + ((size_t)(((ocg * 2 + ich) * 9 + dd) * 4 + kh) << 9)
                 + (g2 * 32 + cc) * 8;
      *(bf16x8*)op = v;
    }
  }
}

// ---------------------------------------------------------------------------
// stem2: conv3x3 128->128 on 32x32 NHWC bf16 + relu + maxpool2 -> 16x16 NHWC.
__global__ __launch_bounds__(256) void conv_stem2_k(
    const bf16_t* __restrict__ act, const bf16_t* __restrict__ wF,
    const float* __restrict__ bias, bf16_t* __restrict__ out)
{
  const int b = blockIdx.x >> 4, ph = blockIdx.x & 15;
  const int y0 = ph * 2;                 // conv rows y0, y0+1
  const int tid = threadIdx.x, lane = tid & 63, wv = tid >> 6;
  const int g = lane >> 5, cc = lane & 31;
  const int wq = wv;                     // 0..3: which 32-oc fragment

  __shared__ bf16_t simg[272 * 64];      // [ich2][4 rows][34 cols][64ch], 34 KB swz

  f32x16 acc[2];
#pragma unroll
  for (int i = 0; i < 2; ++i)
#pragma unroll
    for (int r = 0; r < 16; ++r) acc[i][r] = 0.f;

  const bf16_t* wfb = wF + ((size_t)(wq * 2) * 9 * 4 << 9) + lane * 8;

  // stage rows y0-1..y0+2 (4), cols -1..32 (34), both ic-halves, swizzled
  for (int p = tid; p < 272; p += 256) {
    const int ich = p / 136, r2 = p - ich * 136;
    const int yy = r2 / 34, xx = r2 - yy * 34;
    const int gy = y0 + yy - 1, gx = xx - 1;
    const bool inb = (gy >= 0 && gy < 32 && gx >= 0 && gx < 32);
    const bf16_t* src = act + ((size_t)(b * 1024 + gy * 32 + gx)) * 128 + ich * 64;
#pragma unroll
    for (int j = 0; j < 8; ++j) {
      bf16x8 v = {};
      if (inb) v = *(const bf16x8*)(src + j * 8);
      const int waddr = (p * 128 + j * 16) ^ ((p & 7) << 4);
      *(bf16x8*)((char*)simg + waddr) = v;
    }
  }
  __syncthreads();

#pragma unroll
  for (int ich = 0; ich < 2; ++ich) {
#pragma unroll
    for (int dydx = 0; dydx < 9; ++dydx) {
      const int dy = dydx / 3, dx = dydx - dy * 3;
      const bf16_t* wf = wfb + (((ich * 9 + dydx) * 4) << 9);
#pragma unroll
      for (int kh = 0; kh < 4; ++kh) {
        const bf16x8 a = *(const bf16x8*)(wf + (kh << 9));
#pragma unroll
        for (int r = 0; r < 2; ++r) {
          const int s = ich * 136 + (r + dy) * 34 + cc + dx;
          const int raddr = (s * 128 + (kh * 2 + g) * 16) ^ ((s & 7) << 4);
          const bf16x8 bbv = *(const bf16x8*)((const char*)simg + raddr);
          acc[r] = __builtin_amdgcn_mfma_f32_32x32x16_bf16(a, bbv, acc[r], 0, 0, 0);
        }
      }
    }
  }

  // epilogue: bias -> 2x2 pool -> relu -> NHWC bf16 (pooled row = ph)
  const int pxp = cc >> 1;
  bf16_t* op = out + ((size_t)(b * 256 + ph * 16 + pxp)) * 128;
#pragma unroll
  for (int rq = 0; rq < 4; ++rq) {
    const int oc4 = wq * 32 + rq * 8 + g * 4;
    const f32x4 bi = *(const f32x4*)(bias + oc4);
    bf16x4 qv;
#pragma unroll
    for (int j = 0; j < 4; ++j) {
      const int r = rq * 4 + j;
      float v = fmaxf(acc[0][r], acc[1][r]);
      v = fmaxf(v, __shfl_xor(v, 1));
      qv[j] = (bf16_t)fmaxf(v + bi[j], 0.f);
    }
    if ((cc & 1) == 0) *(bf16x4*)(op + oc4) = qv;
  }
}

// ---------------------------------------------------------------------------
// Expert conv3x3 128->128 on 16x16 NHWC — R14-EXACT measured-best body.
template<int RES>
__global__ __launch_bounds__(256) void conv_exp_k(
    const bf16_t* __restrict__ act, const bf16_t* __restrict__ wF,
    const float* __restrict__ bias, const int* __restrict__ question, int col,
    const bf16_t* __restrict__ res, bf16_t* __restrict__ out)
{
  const int b = blockIdx.x >> 2, ph = blockIdx.x & 3;
  const int y0 = ph * 4;
  const int e = question[b * 8 + col];
  const int tid = threadIdx.x, lane = tid & 63, wv = tid >> 6;
  const int g = lane >> 5, cc = lane & 31;
  const int wq_oc = wv & 1, wq_px = wv >> 1;

  __shared__ bf16_t simg[216 * 64];      // [ich2][6 rows][18 cols][64ch], 27 KB

  f32x16 acc[2];
#pragma unroll
  for (int i = 0; i < 2; ++i)
#pragma unroll
    for (int r = 0; r < 16; ++r) acc[i][r] = 0.f;

  const int px = wq_px * 32 + cc;        // 0..63 within 4x16 strip
  const int sl = (px >> 4) * 18 + (px & 15);

  const bf16_t* wfb = wF + (size_t)e * 147456
                    + (((size_t)(wq_oc * 2) * 2) * 9 * 4 << 9) + lane * 8;

  // stage rows y0-1..y0+4 (6), cols -1..16 (18), both ic-halves, swizzled
  for (int p = tid; p < 216; p += 256) {
    const int ich = p / 108, r2 = p - ich * 108;
    const int yy = r2 / 18, xx = r2 - yy * 18;
    const int gy = y0 + yy - 1, gx = xx - 1;
    const bool inb = (gy >= 0 && gy < 16 && gx >= 0 && gx < 16);
    const bf16_t* src = act + ((size_t)(b * 256 + gy * 16 + gx)) * 128 + ich * 64;
#pragma unroll
    for (int j = 0; j < 8; ++j) {
      bf16x8 v = {};
      if (inb) v = *(const bf16x8*)(src + j * 8);
      const int waddr = (p * 128 + j * 16) ^ ((p & 7) << 4);
      *(bf16x8*)((char*)simg + waddr) = v;
    }
  }
  __syncthreads();

#pragma unroll
  for (int ich = 0; ich < 2; ++ich) {
#pragma unroll
    for (int dydx = 0; dydx < 9; ++dydx) {
      const int dy = dydx / 3, dx = dydx - dy * 3;
      const int sbase = ich * 108 + sl + dy * 18 + dx;
      const bf16_t* wf = wfb + (((ich * 9 + dydx) * 4) << 9);
#pragma unroll
      for (int kh = 0; kh < 4; ++kh) {
        const bf16x8 a0 = *(const bf16x8*)(wf + (kh << 9));
        const bf16x8 a1 = *(const bf16x8*)(wf + 36864 + (kh << 9));
        const int raddr = (sbase * 128 + (kh * 2 + g) * 16) ^ ((sbase & 7) << 4);
        const bf16x8 bbv = *(const bf16x8*)((const char*)simg + raddr);
        acc[0] = __builtin_amdgcn_mfma_f32_32x32x16_bf16(a0, bbv, acc[0], 0, 0, 0);
        acc[1] = __builtin_amdgcn_mfma_f32_32x32x16_bf16(a1, bbv, acc[1], 0, 0, 0);
      }
    }
  }

  const float* bb = bias + e * 128;
  const size_t pixbase = ((size_t)(b * 256 + (y0 + (px >> 4)) * 16 + (px & 15))) * 128;
  bf16_t* op = out + pixbase;
#pragma unroll
  for (int mf = 0; mf < 2; ++mf) {
#pragma unroll
    for (int rq = 0; rq < 4; ++rq) {
      const int oc4 = wq_oc * 64 + mf * 32 + rq * 8 + g * 4;
      const f32x4 bi = *(const f32x4*)(bb + oc4);
      bf16x4 qv;
      bf16x4 rv = {};
      if (RES) rv = *(const bf16x4*)(res + pixbase + oc4);
#pragma unroll
      for (int j = 0; j < 4; ++j) {
        float v = acc[mf][rq * 4 + j] + bi[j];
        if (RES) v += (float)rv[j];
        qv[j] = (bf16_t)fmaxf(v, 0.f);
      }
      *(bf16x4*)(op + oc4) = qv;
    }
  }
}

// ---------------------------------------------------------------------------
// proj 1x1 conv 128->512 + relu + maxpool2, NHWC bf16 in -> f bf16 NCHW
// (128,512,8,8). Fragment weights.
__global__ __launch_bounds__(256) void proj_mfma_k(
    const bf16_t* __restrict__ h, const bf16_t* __restrict__ pwF,
    const float* __restrict__ pb, bf16_t* __restrict__ f)
{
  const int b = blockIdx.x >> 2, ocg = blockIdx.x & 3;
  const int tid = threadIdx.x, lane = tid & 63, wv = tid >> 6;
  const int g = lane >> 5, cc = lane & 31;
  const int wq_oc = wv & 1, wq_px = wv >> 1;

  __shared__ bf16_t simg[256 * 64];

  f32x16 acc[2][4];
#pragma unroll
  for (int i = 0; i < 2; ++i)
#pragma unroll
    for (int j = 0; j < 4; ++j)
#pragma unroll
      for (int r = 0; r < 16; ++r) acc[i][j][r] = 0.f;

  const int px0 = wq_px * 128 + cc;
  const int og0 = ocg * 4 + wq_oc * 2;
  const bf16_t* pfb = pwF + (((size_t)og0 * 2 * 4) << 9) + lane * 8;

  for (int ich = 0; ich < 2; ++ich) {
    __syncthreads();
    {
      const int p = tid;
      const bf16_t* src = h + ((size_t)(b * 256 + p)) * 128 + ich * 64;
#pragma unroll
      for (int j = 0; j < 8; ++j) {
        bf16x8 v = *(const bf16x8*)(src + j * 8);
        const int waddr = (p * 128 + j * 16) ^ ((p & 7) << 4);
        *(bf16x8*)((char*)simg + waddr) = v;
      }
    }
    __syncthreads();

#pragma unroll
    for (int kh = 0; kh < 4; ++kh) {
      const bf16x8 a0 = *(const bf16x8*)(pfb + ((ich * 4 + kh) << 9));
      const bf16x8 a1 = *(const bf16x8*)(pfb + 4096 + ((ich * 4 + kh) << 9));
#pragma unroll
      for (int nf = 0; nf < 4; ++nf) {
        const int s = px0 + nf * 32;
        const int raddr = (s * 128 + (kh * 2 + g) * 16) ^ ((s & 7) << 4);
        const bf16x8 bb = *(const bf16x8*)((const char*)simg + raddr);
        acc[0][nf] = __builtin_amdgcn_mfma_f32_32x32x16_bf16(a0, bb, acc[0][nf], 0, 0, 0);
        acc[1][nf] = __builtin_amdgcn_mfma_f32_32x32x16_bf16(a1, bb, acc[1][nf], 0, 0, 0);
      }
    }
  }

#pragma unroll
  for (int mf = 0; mf < 2; ++mf) {
#pragma unroll
    for (int nf = 0; nf < 4; ++nf) {
      const int px = px0 + nf * 32;
      const int x = px & 15;
      const int py = wq_px * 4 + nf;
      const int pxp = x >> 1;
#pragma unroll
      for (int r = 0; r < 16; ++r) {
        float v = acc[mf][nf][r];
        v = fmaxf(v, __shfl_xor(v, 1));
        v = fmaxf(v, __shfl_xor(v, 16));
        const int oc = ocg * 128 + wq_oc * 64 + mf * 32 + (r & 3) + 8 * (r >> 2) + 4 * g;
        v = fmaxf(v + pb[oc], 0.f);
        if ((cc & 17) == 0)
          f[((size_t)(b * 512 + oc)) * 64 + py * 8 + pxp] = (bf16_t)v;
      }
    }
  }
}

// ---------------------------------------------------------------------------
// fc1 as bf16 MFMA GEMM (R25 measured-best config):
// grid = (16 n-tiles of 64) x (32 k-slices of 1024); 256 thr = 4 waves (2m x 2n).
__global__ __launch_bounds__(256) void fc1_mfma_k(
    const bf16_t* __restrict__ A, const float* __restrict__ W,
    float* __restrict__ part)
{
  const int nt = blockIdx.x;        // 0..15
  const int ks = blockIdx.y;        // 0..31
  const int n0 = nt * 64;
  const int k0 = ks * 1024;
  const int tid = threadIdx.x, lane = tid & 63, wv = tid >> 6;
  const int g = lane >> 5, cc = lane & 31;
  const int mh = wv & 1, nh = wv >> 1;

  __shared__ char sA[16384];   // [128][64] bf16, XOR-swizzled
  __shared__ char sB[8192];    // [64][64] bf16, XOR-swizzled

  f32x16 acc0, acc1;
#pragma unroll
  for (int r = 0; r < 16; ++r) { acc0[r] = 0.f; acc1[r] = 0.f; }

  for (int t = 0; t < 16; ++t) {   // 16 K-tiles of 64
    __syncthreads();
#pragma unroll
    for (int i = 0; i < 4; ++i) {
      const int c = tid + i * 256;
      const int row = c >> 3, ko = c & 7;
      bf16x8 v = *(const bf16x8*)(A + (size_t)row * 32768 + k0 + t * 64 + ko * 8);
      const int wa = (row * 128 + ko * 16) ^ ((row & 7) << 4);
      *(bf16x8*)(sA + wa) = v;
    }
#pragma unroll
    for (int i = 0; i < 2; ++i) {
      const int c = tid + i * 256;
      const int row = c >> 3, ko = c & 7;
      const float* src = W + (size_t)(n0 + row) * 32768 + k0 + t * 64 + ko * 8;
      f32x4 u0 = *(const f32x4*)src;
      f32x4 u1 = *(const f32x4*)(src + 4);
      bf16x8 v;
#pragma unroll
      for (int j = 0; j < 4; ++j) { v[j] = (bf16_t)u0[j]; v[4 + j] = (bf16_t)u1[j]; }
      const int wa = (row * 128 + ko * 16) ^ ((row & 7) << 4);
      *(bf16x8*)(sB + wa) = v;
    }
    __syncthreads();
#pragma unroll
    for (int kss = 0; kss < 4; ++kss) {
      const int kb = kss * 32 + g * 16;
      const int rA0 = mh * 64 + cc, rA1 = rA0 + 32;
      const bf16x8 a0 = *(const bf16x8*)(sA + ((rA0 * 128 + kb) ^ ((rA0 & 7) << 4)));
      const bf16x8 a1 = *(const bf16x8*)(sA + ((rA1 * 128 + kb) ^ ((rA1 & 7) << 4)));
      const int rB = nh * 32 + cc;
      const bf16x8 bb = *(const bf16x8*)(sB + ((rB * 128 + kb) ^ ((rB & 7) << 4)));
      acc0 = __builtin_amdgcn_mfma_f32_32x32x16_bf16(a0, bb, acc0, 0, 0, 0);
      acc1 = __builtin_amdgcn_mfma_f32_32x32x16_bf16(a1, bb, acc1, 0, 0, 0);
    }
  }

  float* pp = part + ((size_t)ks * 128) * 1024 + n0 + nh * 32 + cc;
#pragma unroll
  for (int r = 0; r < 16; ++r) {
    const int m0 = mh * 64 + (r & 3) + 8 * (r >> 2) + 4 * g;
    pp[(size_t)m0 * 1024] = acc0[r];
    pp[(size_t)(m0 + 32) * 1024] = acc1[r];
  }
}

// ---------------------------------------------------------------------------
// Fused head: per output row m, s_j = relu(fc1_b[j] + sum_ks part[ks][m][j])
// (same ks order as old fc1_red), then fc2 dot with the same j-stride-256
// accumulation order as the old fc2 — bitwise-identical to the 2-kernel form.
__global__ __launch_bounds__(256) void fc_head_k(
    const float* __restrict__ part, const float* __restrict__ b1v,
    const float* __restrict__ w2, const float* __restrict__ b2,
    float* __restrict__ out)
{
  const int m = blockIdx.x;          // 0..127
  const int tid = threadIdx.x;
  float a0 = 0.f, a1 = 0.f;
  for (int j = tid; j < 1024; j += 256) {
    float s = b1v[j];
#pragma unroll
    for (int ks = 0; ks < 32; ++ks)
      s += part[((size_t)ks * 128 + m) * 1024 + j];
    s = fmaxf(s, 0.f);
    a0 = fmaf(s, w2[j], a0);
    a1 = fmaf(s, w2[1024 + j], a1);
  }
#pragma unroll
  for (int o = 32; o > 0; o >>= 1) {
    a0 += __shfl_down(a0, o);
    a1 += __shfl_down(a1, o);
  }
  __shared__ float r0[4], r1[4];
  const int wid = tid >> 6;
  if ((tid & 63) == 0) { r0[wid] = a0; r1[wid] = a1; }
  __syncthreads();
  if (tid == 0) {
    out[(size_t)m * 2 + 0] = r0[0] + r0[1] + r0[2] + r0[3] + b2[0];
    out[(size_t)m * 2 + 1] = r1[0] + r1[1] + r1[2] + r1[3] + b2[1];
  }
}

// ---------------------------------------------------------------------------
extern "C" void kernel_launch(void* const* d_in, const int* in_sizes, int n_in,
                              void* d_out, int out_size, void* d_ws, size_t ws_size,
                              hipStream_t stream)
{
  const float* image    = (const float*)d_in[0];
  const int*   question = (const int*)  d_in[1];
  const float* stem_w1  = (const float*)d_in[2];
  const float* stem_b1  = (const float*)d_in[3];
  const float* stem_w2  = (const float*)d_in[4];
  const float* stem_b2  = (const float*)d_in[5];
  const float* exp_w1   = (const float*)d_in[6];
  const float* exp_b1   = (const float*)d_in[7];
  const float* exp_w2   = (const float*)d_in[8];
  const float* exp_b2   = (const float*)d_in[9];
  const float* proj_w   = (const float*)d_in[10];
  const float* proj_b   = (const float*)d_in[11];
  const float* fc1_w    = (const float*)d_in[12];
  const float* fc1_b    = (const float*)d_in[13];
  const float* fc2_w    = (const float*)d_in[14];
  const float* fc2_b    = (const float*)d_in[15];
  float* out = (float*)d_out;

  char* base = (char*)d_ws;
  bf16_t* actA   = (bf16_t*)(base + 33554432);         // 33,554,432 B (NHWC 32x32)
  bf16_t* actH   = (bf16_t*)(base + 67108864);         //  8,388,608 B (NHWC 16x16)
  bf16_t* actT   = (bf16_t*)(base + 75497472);         //  8,388,608 B
  bf16_t* wT1    = (bf16_t*)(base + 83886080);         //  4,718,592 B (frag)
  bf16_t* wT2    = (bf16_t*)(base + 88604672);         //  4,718,592 B (frag)
  bf16_t* wTs2   = (bf16_t*)(base + 93323264);         //    294,912 B (frag)
  bf16_t* pwT    = (bf16_t*)(base + 93618176);         //    131,072 B (frag)
  // region0 reuse: f bf16, fc1 partials (32 slices)
  bf16_t* fbf  = (bf16_t*)base;                        //  8,388,608 B
  float*  part = (float*)(base + 8388608);             // 16,777,216 B (32x128x1024)

  // fused weight prep || stem1 (prep re-blocked for contiguous reads)
  prep_stem1_k<<<2376, 256, 0, stream>>>(exp_w1, exp_w2, stem_w2, proj_w,
                                         wT1, wT2, wTs2, pwT,
                                         image, stem_w1, stem_b1, actA);

  conv_stem2_k<<<2048, 256, 0, stream>>>(actA, wTs2, stem_b2, actH);

  // expert residual blocks, routing cols (3,4,6,7,5)
  const int cols[5] = {3, 4, 6, 7, 5};
  for (int i = 0; i < 5; ++i) {
    conv_exp_k<0><<<512, 256, 0, stream>>>(actH, wT1, exp_b1, question, cols[i],
                                           nullptr, actT);
    conv_exp_k<1><<<512, 256, 0, stream>>>(actT, wT2, exp_b2, question, cols[i],
                                           actH, actH);
  }

  // head
  proj_mfma_k<<<512, 256, 0, stream>>>(actH, pwT, proj_b, fbf);
  fc1_mfma_k<<<dim3(16, 32), 256, 0, stream>>>(fbf, fc1_w, part);
  fc_head_k<<<128, 256, 0, stream>>>(part, fc1_b, fc2_w, fc2_b, out);
}

// Round 34
// 350.025 us; speedup vs baseline: 1.0441x; 1.0068x over previous
//
#include <hip/hip_runtime.h>
#include <hip/hip_bf16.h>
#include <cstdint>
#include <cstddef>

// SimpleModuleNet MoE CNN forward — bf16 MFMA implicit-GEMM (R33-best + stem2 4-row).
// B=128, C=128, E=16, H=W=64, PROJ=512, FC=1024, NANS=2
//
// MFMA v_mfma_f32_32x32x16_bf16; A,B fragments use the SAME slot convention
// k = (lane>>5)*8 + j => any k-permutation cancels. C/D layout (HW-verified):
// col = lane&31, row = (r&3)+8*(r>>2)+4*(lane>>5).
//
// Ledger: wins = frag weights+TLP(R10), stem2 reshape(R14), prep fuse(R20),
// prep||stem1(R23), prep contiguous re-block(R25), fused fc head(R33, 352.4us).
// Falsified/parked: ic-split, 1A:2ds, big-unroll stem2, stem1 oc8, stem1 MFMA
// im2col, fc1 {wide-N, narrow-N, ks=64, reg-dbuf} (parked ~74us), W->bf16
// convert anywhere. This round: stem2 4-conv-row tiles (2A:2ds:4MFMA, the
// conv_exp-winning shape): grid 2048->1024, read-amp 2.0->1.5, 2x MFMA/ds.

typedef __bf16 bf16_t;
typedef __attribute__((ext_vector_type(4))) bf16_t bf16x4;
typedef __attribute__((ext_vector_type(8))) bf16_t bf16x8;
typedef __attribute__((ext_vector_type(16))) float f32x16;
typedef __attribute__((ext_vector_type(4))) float f32x4;

// ---------------------------------------------------------------------------
// Fused weight-prep + stem1 (R25-exact).
// blocks [0,128): exp_w1   [128,256): exp_w2   [256,264): stem_w2
// blocks [264,328): proj   [328,2376): stem1
__global__ __launch_bounds__(256) void prep_stem1_k(
    const float* __restrict__ exp_w1, const float* __restrict__ exp_w2,
    const float* __restrict__ stem_w2, const float* __restrict__ proj_w,
    bf16_t* __restrict__ wT1, bf16_t* __restrict__ wT2,
    bf16_t* __restrict__ wTs2, bf16_t* __restrict__ pwT,
    const float* __restrict__ img, const float* __restrict__ w1,
    const float* __restrict__ b1, bf16_t* __restrict__ s1out)
{
  alignas(16) __shared__ char smem[37120];   // union: prep sW[16][580] f32 /
                                             // stem1 sImg(4104B)+pad+sOut(16384B)
  int bid = blockIdx.x;
  const int tid = threadIdx.x;

  if (bid >= 328) {
    // ---- stem1 branch: conv3x3 (3->128) + relu + maxpool2 -> NHWC bf16 ----
    bid -= 328;                           // 128 b * 16 tiles
    float* sImg = (float*)smem;           // [3][18][19] floats (idx ic*342+rr*19+cc)
    char*  sOut = smem + 4112;            // [64 px][128 oc] bf16, XOR-swizzled
    const int b = bid >> 4, t = bid & 15;
    const int ty0p = (t >> 2) * 8, tx0p = (t & 3) * 8;
    const int lane = tid & 63;
    const int wvbase = __builtin_amdgcn_readfirstlane(tid >> 6) * 32;

    for (int s = tid; s < 972; s += 256) {
      const int ic = s / 324, r2 = s - ic * 324;
      const int rr = r2 / 18, cc = r2 - rr * 18;
      const int gy = 2 * ty0p - 1 + rr, gx = 2 * tx0p - 1 + cc;
      float v = 0.f;
      if (gy >= 0 && gy < 64 && gx >= 0 && gx < 64)
        v = img[(((size_t)b * 3 + ic) * 64 + gy) * 64 + gx];
      sImg[ic * 342 + rr * 19 + cc] = v;
    }
    __syncthreads();

    const int ppy = lane >> 3, ppx = lane & 7;
    const int swz = (lane & 15) << 3;
    char* orow = sOut + lane * 256;

    for (int oc8 = 0; oc8 < 32; oc8 += 8) {
      float acc[8][2][2];
#pragma unroll
      for (int q = 0; q < 8; ++q) {
        const float bv = b1[wvbase + oc8 + q];
#pragma unroll
        for (int i = 0; i < 2; ++i)
#pragma unroll
          for (int jj = 0; jj < 2; ++jj) acc[q][i][jj] = bv;
      }
#pragma unroll
      for (int ic = 0; ic < 3; ++ic)
#pragma unroll
        for (int dy = 0; dy < 3; ++dy)
#pragma unroll
          for (int dx = 0; dx < 3; ++dx) {
            const float p00 = sImg[ic * 342 + (2 * ppy + dy) * 19 + 2 * ppx + dx];
            const float p01 = sImg[ic * 342 + (2 * ppy + dy) * 19 + 2 * ppx + dx + 1];
            const float p10 = sImg[ic * 342 + (2 * ppy + dy + 1) * 19 + 2 * ppx + dx];
            const float p11 = sImg[ic * 342 + (2 * ppy + dy + 1) * 19 + 2 * ppx + dx + 1];
#pragma unroll
            for (int q = 0; q < 8; ++q) {
              const float wv2 = w1[(wvbase + oc8 + q) * 27 + ic * 9 + dy * 3 + dx];
              acc[q][0][0] = fmaf(p00, wv2, acc[q][0][0]);
              acc[q][0][1] = fmaf(p01, wv2, acc[q][0][1]);
              acc[q][1][0] = fmaf(p10, wv2, acc[q][1][0]);
              acc[q][1][1] = fmaf(p11, wv2, acc[q][1][1]);
            }
          }
#pragma unroll
      for (int h4 = 0; h4 < 8; h4 += 4) {
        bf16x4 qv;
#pragma unroll
        for (int j = 0; j < 4; ++j) {
          const int q = h4 + j;
          const float mx = fmaxf(fmaxf(acc[q][0][0], acc[q][0][1]),
                                 fmaxf(acc[q][1][0], acc[q][1][1]));
          qv[j] = (bf16_t)fmaxf(mx, 0.f);
        }
        *(bf16x4*)(orow + (((wvbase + oc8 + h4) * 2) ^ swz)) = qv;
      }
    }
    __syncthreads();

#pragma unroll
    for (int it = 0; it < 4; ++it) {
      const int idx = it * 256 + tid;
      const int px = idx >> 4, ch8 = idx & 15;
      const int sw = (px & 15) << 3;
      const char* rb = sOut + px * 256;
      bf16x4 lo = *(const bf16x4*)(rb + ((ch8 * 16) ^ sw));
      bf16x4 hi = *(const bf16x4*)(rb + ((ch8 * 16 + 8) ^ sw));
      bf16x8 v;
#pragma unroll
      for (int j = 0; j < 4; ++j) { v[j] = lo[j]; v[4 + j] = hi[j]; }
      const int gpy = ty0p + (px >> 3), gpx = tx0p + (px & 7);
      *(bf16x8*)(s1out + ((size_t)(b * 1024 + gpy * 32 + gpx)) * 128 + ch8 * 8) = v;
    }
    return;
  }

  if (bid >= 264) {
    // ---- proj branch: [512 oc][128 ic] fp32 -> fragment order ----
    const int base = (bid - 264) * 1024 + tid;
#pragma unroll
    for (int it = 0; it < 4; ++it) {
      const int idx = base + it * 256;     // 0..65535 = oc*128 + ic
      const int oc = idx >> 7, ic = idx & 127;
      const int og = oc >> 5, cc2 = oc & 31;
      const int ich2 = ic >> 6, icl = ic & 63;
      const int kh2 = icl >> 4, g2 = (icl >> 3) & 1, j2 = icl & 7;
      const int off = ((((og * 2 + ich2) * 4 + kh2) << 9)) + ((g2 << 5) + cc2) * 8 + j2;
      pwT[off] = (bf16_t)proj_w[(size_t)oc * 128 + ic];
    }
    return;
  }

  // ---- conv weight prep: block = (e,ocg,ich); CONTIGUOUS reads via LDS ----
  const float* in;
  bf16_t* out;
  if (bid < 128)      { in = exp_w1;  out = wT1; }
  else if (bid < 256) { in = exp_w2;  out = wT2;  bid -= 128; }
  else                { in = stem_w2; out = wTs2; bid -= 256; }   // e=0 only
  const int e   = bid >> 3;
  const int rem = bid & 7;
  const int ocg = rem >> 1, ich = rem & 1;

  float* sW = (float*)smem;                // [16][580] floats (row stride 580)
  bf16_t* outb = out + (size_t)e * 147456;

  for (int h = 0; h < 2; ++h) {
    if (h) __syncthreads();                // previous half's readers done
    for (int idx = tid; idx < 2304; idx += 256) {
      const int r16 = idx / 144, q = idx - r16 * 144;
      const float* src = in + (size_t)(e * 128 + ocg * 32 + h * 16 + r16) * 1152
                       + ich * 576 + q * 4;
      *(f32x4*)(&sW[r16 * 580 + q * 4]) = *(const f32x4*)src;
    }
    __syncthreads();
    for (int c = tid; c < 1152; c += 256) {
      const int dd  = c >> 7;
      const int kh  = (c >> 5) & 3;
      const int g2  = (c >> 4) & 1;
      const int c16 = c & 15;
      const int cc  = h * 16 + c16;
      bf16x8 v;
#pragma unroll
      for (int j = 0; j < 8; ++j)
        v[j] = (bf16_t)sW[c16 * 580 + (kh * 16 + g2 * 8 + j) * 9 + dd];
      bf16_t* op = outb + ((size_t)(((ocg * 2 + ich) * 9 + dd) * 4 + kh) << 9)
                 + (g2 * 32 + cc) * 8;
      *(bf16x8*)op = v;
    }
  }
}

// ---------------------------------------------------------------------------
// stem2: conv3x3 128->128 on 32x32 NHWC bf16 + relu + maxpool2 -> 16x16 NHWC.
// 4-conv-row tiles (conv_exp-winning shape): grid 1024 (b*8 + ph), wave =
// (oc-half wq_oc, pool-row-pair wq_px); per k-step 2A:2ds:4MFMA.
__global__ __launch_bounds__(256) void conv_stem2_k(
    const bf16_t* __restrict__ act, const bf16_t* __restrict__ wF,
    const float* __restrict__ bias, bf16_t* __restrict__ out)
{
  const int b = blockIdx.x >> 3, ph = blockIdx.x & 7;
  const int y0 = ph * 4;                 // conv rows y0..y0+3
  const int tid = threadIdx.x, lane = tid & 63, wv = tid >> 6;
  const int g = lane >> 5, cc = lane & 31;
  const int wq_oc = wv & 1, wq_px = wv >> 1;

  __shared__ bf16_t simg[408 * 64];      // [ich2][6 rows][34 cols][64ch], 52 KB swz

  f32x16 acc[2][2];                      // [mf][r]
#pragma unroll
  for (int i = 0; i < 2; ++i)
#pragma unroll
    for (int j = 0; j < 2; ++j)
#pragma unroll
      for (int r = 0; r < 16; ++r) acc[i][j][r] = 0.f;

  const bf16_t* wfb = wF + ((size_t)(wq_oc * 2 * 2) * 9 * 4 << 9) + lane * 8;

  // stage rows y0-1..y0+4 (6), cols -1..32 (34), both ic-halves, swizzled
  for (int p = tid; p < 408; p += 256) {
    const int ich = p / 204, r2 = p - ich * 204;
    const int yy = r2 / 34, xx = r2 - yy * 34;
    const int gy = y0 + yy - 1, gx = xx - 1;
    const bool inb = (gy >= 0 && gy < 32 && gx >= 0 && gx < 32);
    const bf16_t* src = act + ((size_t)(b * 1024 + gy * 32 + gx)) * 128 + ich * 64;
#pragma unroll
    for (int j = 0; j < 8; ++j) {
      bf16x8 v = {};
      if (inb) v = *(const bf16x8*)(src + j * 8);
      const int waddr = (p * 128 + j * 16) ^ ((p & 7) << 4);
      *(bf16x8*)((char*)simg + waddr) = v;
    }
  }
  __syncthreads();

#pragma unroll
  for (int ich = 0; ich < 2; ++ich) {
#pragma unroll
    for (int dydx = 0; dydx < 9; ++dydx) {
      const int dy = dydx / 3, dx = dydx - dy * 3;
      const bf16_t* wf = wfb + (((ich * 9 + dydx) * 4) << 9);
#pragma unroll
      for (int kh = 0; kh < 4; ++kh) {
        const bf16x8 a0 = *(const bf16x8*)(wf + (kh << 9));
        const bf16x8 a1 = *(const bf16x8*)(wf + 36864 + (kh << 9));
#pragma unroll
        for (int r = 0; r < 2; ++r) {
          const int s = ich * 204 + (2 * wq_px + r + dy) * 34 + cc + dx;
          const int raddr = (s * 128 + (kh * 2 + g) * 16) ^ ((s & 7) << 4);
          const bf16x8 bbv = *(const bf16x8*)((const char*)simg + raddr);
          acc[0][r] = __builtin_amdgcn_mfma_f32_32x32x16_bf16(a0, bbv, acc[0][r], 0, 0, 0);
          acc[1][r] = __builtin_amdgcn_mfma_f32_32x32x16_bf16(a1, bbv, acc[1][r], 0, 0, 0);
        }
      }
    }
  }

  // epilogue: 2x2 pool (vertical r-pair + horizontal shfl_xor 1) + bias + relu
  const int pxp = cc >> 1;
  bf16_t* op = out + ((size_t)(b * 256 + (ph * 2 + wq_px) * 16 + pxp)) * 128;
#pragma unroll
  for (int mf = 0; mf < 2; ++mf) {
#pragma unroll
    for (int rq = 0; rq < 4; ++rq) {
      const int oc4 = wq_oc * 64 + mf * 32 + rq * 8 + g * 4;
      const f32x4 bi = *(const f32x4*)(bias + oc4);
      bf16x4 qv;
#pragma unroll
      for (int j = 0; j < 4; ++j) {
        const int r = rq * 4 + j;
        float v = fmaxf(acc[mf][0][r], acc[mf][1][r]);
        v = fmaxf(v, __shfl_xor(v, 1));
        qv[j] = (bf16_t)fmaxf(v + bi[j], 0.f);
      }
      if ((cc & 1) == 0) *(bf16x4*)(op + oc4) = qv;
    }
  }
}

// ---------------------------------------------------------------------------
// Expert conv3x3 128->128 on 16x16 NHWC — R14-EXACT measured-best body.
template<int RES>
__global__ __launch_bounds__(256) void conv_exp_k(
    const bf16_t* __restrict__ act, const bf16_t* __restrict__ wF,
    const float* __restrict__ bias, const int* __restrict__ question, int col,
    const bf16_t* __restrict__ res, bf16_t* __restrict__ out)
{
  const int b = blockIdx.x >> 2, ph = blockIdx.x & 3;
  const int y0 = ph * 4;
  const int e = question[b * 8 + col];
  const int tid = threadIdx.x, lane = tid & 63, wv = tid >> 6;
  const int g = lane >> 5, cc = lane & 31;
  const int wq_oc = wv & 1, wq_px = wv >> 1;

  __shared__ bf16_t simg[216 * 64];      // [ich2][6 rows][18 cols][64ch], 27 KB

  f32x16 acc[2];
#pragma unroll
  for (int i = 0; i < 2; ++i)
#pragma unroll
    for (int r = 0; r < 16; ++r) acc[i][r] = 0.f;

  const int px = wq_px * 32 + cc;        // 0..63 within 4x16 strip
  const int sl = (px >> 4) * 18 + (px & 15);

  const bf16_t* wfb = wF + (size_t)e * 147456
                    + (((size_t)(wq_oc * 2) * 2) * 9 * 4 << 9) + lane * 8;

  // stage rows y0-1..y0+4 (6), cols -1..16 (18), both ic-halves, swizzled
  for (int p = tid; p < 216; p += 256) {
    const int ich = p / 108, r2 = p - ich * 108;
    const int yy = r2 / 18, xx = r2 - yy * 18;
    const int gy = y0 + yy - 1, gx = xx - 1;
    const bool inb = (gy >= 0 && gy < 16 && gx >= 0 && gx < 16);
    const bf16_t* src = act + ((size_t)(b * 256 + gy * 16 + gx)) * 128 + ich * 64;
#pragma unroll
    for (int j = 0; j < 8; ++j) {
      bf16x8 v = {};
      if (inb) v = *(const bf16x8*)(src + j * 8);
      const int waddr = (p * 128 + j * 16) ^ ((p & 7) << 4);
      *(bf16x8*)((char*)simg + waddr) = v;
    }
  }
  __syncthreads();

#pragma unroll
  for (int ich = 0; ich < 2; ++ich) {
#pragma unroll
    for (int dydx = 0; dydx < 9; ++dydx) {
      const int dy = dydx / 3, dx = dydx - dy * 3;
      const int sbase = ich * 108 + sl + dy * 18 + dx;
      const bf16_t* wf = wfb + (((ich * 9 + dydx) * 4) << 9);
#pragma unroll
      for (int kh = 0; kh < 4; ++kh) {
        const bf16x8 a0 = *(const bf16x8*)(wf + (kh << 9));
        const bf16x8 a1 = *(const bf16x8*)(wf + 36864 + (kh << 9));
        const int raddr = (sbase * 128 + (kh * 2 + g) * 16) ^ ((sbase & 7) << 4);
        const bf16x8 bbv = *(const bf16x8*)((const char*)simg + raddr);
        acc[0] = __builtin_amdgcn_mfma_f32_32x32x16_bf16(a0, bbv, acc[0], 0, 0, 0);
        acc[1] = __builtin_amdgcn_mfma_f32_32x32x16_bf16(a1, bbv, acc[1], 0, 0, 0);
      }
    }
  }

  const float* bb = bias + e * 128;
  const size_t pixbase = ((size_t)(b * 256 + (y0 + (px >> 4)) * 16 + (px & 15))) * 128;
  bf16_t* op = out + pixbase;
#pragma unroll
  for (int mf = 0; mf < 2; ++mf) {
#pragma unroll
    for (int rq = 0; rq < 4; ++rq) {
      const int oc4 = wq_oc * 64 + mf * 32 + rq * 8 + g * 4;
      const f32x4 bi = *(const f32x4*)(bb + oc4);
      bf16x4 qv;
      bf16x4 rv = {};
      if (RES) rv = *(const bf16x4*)(res + pixbase + oc4);
#pragma unroll
      for (int j = 0; j < 4; ++j) {
        float v = acc[mf][rq * 4 + j] + bi[j];
        if (RES) v += (float)rv[j];
        qv[j] = (bf16_t)fmaxf(v, 0.f);
      }
      *(bf16x4*)(op + oc4) = qv;
    }
  }
}

// ---------------------------------------------------------------------------
// proj 1x1 conv 128->512 + relu + maxpool2, NHWC bf16 in -> f bf16 NCHW
// (128,512,8,8). Fragment weights.
__global__ __launch_bounds__(256) void proj_mfma_k(
    const bf16_t* __restrict__ h, const bf16_t* __restrict__ pwF,
    const float* __restrict__ pb, bf16_t* __restrict__ f)
{
  const int b = blockIdx.x >> 2, ocg = blockIdx.x & 3;
  const int tid = threadIdx.x, lane = tid & 63, wv = tid >> 6;
  const int g = lane >> 5, cc = lane & 31;
  const int wq_oc = wv & 1, wq_px = wv >> 1;

  __shared__ bf16_t simg[256 * 64];

  f32x16 acc[2][4];
#pragma unroll
  for (int i = 0; i < 2; ++i)
#pragma unroll
    for (int j = 0; j < 4; ++j)
#pragma unroll
      for (int r = 0; r < 16; ++r) acc[i][j][r] = 0.f;

  const int px0 = wq_px * 128 + cc;
  const int og0 = ocg * 4 + wq_oc * 2;
  const bf16_t* pfb = pwF + (((size_t)og0 * 2 * 4) << 9) + lane * 8;

  for (int ich = 0; ich < 2; ++ich) {
    __syncthreads();
    {
      const int p = tid;
      const bf16_t* src = h + ((size_t)(b * 256 + p)) * 128 + ich * 64;
#pragma unroll
      for (int j = 0; j < 8; ++j) {
        bf16x8 v = *(const bf16x8*)(src + j * 8);
        const int waddr = (p * 128 + j * 16) ^ ((p & 7) << 4);
        *(bf16x8*)((char*)simg + waddr) = v;
      }
    }
    __syncthreads();

#pragma unroll
    for (int kh = 0; kh < 4; ++kh) {
      const bf16x8 a0 = *(const bf16x8*)(pfb + ((ich * 4 + kh) << 9));
      const bf16x8 a1 = *(const bf16x8*)(pfb + 4096 + ((ich * 4 + kh) << 9));
#pragma unroll
      for (int nf = 0; nf < 4; ++nf) {
        const int s = px0 + nf * 32;
        const int raddr = (s * 128 + (kh * 2 + g) * 16) ^ ((s & 7) << 4);
        const bf16x8 bb = *(const bf16x8*)((const char*)simg + raddr);
        acc[0][nf] = __builtin_amdgcn_mfma_f32_32x32x16_bf16(a0, bb, acc[0][nf], 0, 0, 0);
        acc[1][nf] = __builtin_amdgcn_mfma_f32_32x32x16_bf16(a1, bb, acc[1][nf], 0, 0, 0);
      }
    }
  }

#pragma unroll
  for (int mf = 0; mf < 2; ++mf) {
#pragma unroll
    for (int nf = 0; nf < 4; ++nf) {
      const int px = px0 + nf * 32;
      const int x = px & 15;
      const int py = wq_px * 4 + nf;
      const int pxp = x >> 1;
#pragma unroll
      for (int r = 0; r < 16; ++r) {
        float v = acc[mf][nf][r];
        v = fmaxf(v, __shfl_xor(v, 1));
        v = fmaxf(v, __shfl_xor(v, 16));
        const int oc = ocg * 128 + wq_oc * 64 + mf * 32 + (r & 3) + 8 * (r >> 2) + 4 * g;
        v = fmaxf(v + pb[oc], 0.f);
        if ((cc & 17) == 0)
          f[((size_t)(b * 512 + oc)) * 64 + py * 8 + pxp] = (bf16_t)v;
      }
    }
  }
}

// ---------------------------------------------------------------------------
// fc1 as bf16 MFMA GEMM (R25 measured-best config):
// grid = (16 n-tiles of 64) x (32 k-slices of 1024); 256 thr = 4 waves (2m x 2n).
__global__ __launch_bounds__(256) void fc1_mfma_k(
    const bf16_t* __restrict__ A, const float* __restrict__ W,
    float* __restrict__ part)
{
  const int nt = blockIdx.x;        // 0..15
  const int ks = blockIdx.y;        // 0..31
  const int n0 = nt * 64;
  const int k0 = ks * 1024;
  const int tid = threadIdx.x, lane = tid & 63, wv = tid >> 6;
  const int g = lane >> 5, cc = lane & 31;
  const int mh = wv & 1, nh = wv >> 1;

  __shared__ char sA[16384];   // [128][64] bf16, XOR-swizzled
  __shared__ char sB[8192];    // [64][64] bf16, XOR-swizzled

  f32x16 acc0, acc1;
#pragma unroll
  for (int r = 0; r < 16; ++r) { acc0[r] = 0.f; acc1[r] = 0.f; }

  for (int t = 0; t < 16; ++t) {   // 16 K-tiles of 64
    __syncthreads();
#pragma unroll
    for (int i = 0; i < 4; ++i) {
      const int c = tid + i * 256;
      const int row = c >> 3, ko = c & 7;
      bf16x8 v = *(const bf16x8*)(A + (size_t)row * 32768 + k0 + t * 64 + ko * 8);
      const int wa = (row * 128 + ko * 16) ^ ((row & 7) << 4);
      *(bf16x8*)(sA + wa) = v;
    }
#pragma unroll
    for (int i = 0; i < 2; ++i) {
      const int c = tid + i * 256;
      const int row = c >> 3, ko = c & 7;
      const float* src = W + (size_t)(n0 + row) * 32768 + k0 + t * 64 + ko * 8;
      f32x4 u0 = *(const f32x4*)src;
      f32x4 u1 = *(const f32x4*)(src + 4);
      bf16x8 v;
#pragma unroll
      for (int j = 0; j < 4; ++j) { v[j] = (bf16_t)u0[j]; v[4 + j] = (bf16_t)u1[j]; }
      const int wa = (row * 128 + ko * 16) ^ ((row & 7) << 4);
      *(bf16x8*)(sB + wa) = v;
    }
    __syncthreads();
#pragma unroll
    for (int kss = 0; kss < 4; ++kss) {
      const int kb = kss * 32 + g * 16;
      const int rA0 = mh * 64 + cc, rA1 = rA0 + 32;
      const bf16x8 a0 = *(const bf16x8*)(sA + ((rA0 * 128 + kb) ^ ((rA0 & 7) << 4)));
      const bf16x8 a1 = *(const bf16x8*)(sA + ((rA1 * 128 + kb) ^ ((rA1 & 7) << 4)));
      const int rB = nh * 32 + cc;
      const bf16x8 bb = *(const bf16x8*)(sB + ((rB * 128 + kb) ^ ((rB & 7) << 4)));
      acc0 = __builtin_amdgcn_mfma_f32_32x32x16_bf16(a0, bb, acc0, 0, 0, 0);
      acc1 = __builtin_amdgcn_mfma_f32_32x32x16_bf16(a1, bb, acc1, 0, 0, 0);
    }
  }

  float* pp = part + ((size_t)ks * 128) * 1024 + n0 + nh * 32 + cc;
#pragma unroll
  for (int r = 0; r < 16; ++r) {
    const int m0 = mh * 64 + (r & 3) + 8 * (r >> 2) + 4 * g;
    pp[(size_t)m0 * 1024] = acc0[r];
    pp[(size_t)(m0 + 32) * 1024] = acc1[r];
  }
}

// ---------------------------------------------------------------------------
// Fused head: per output row m, s_j = relu(fc1_b[j] + sum_ks part[ks][m][j]),
// then fc2 dot with j-stride-256 order — bitwise-identical to 2-kernel form.
__global__ __launch_bounds__(256) void fc_head_k(
    const float* __restrict__ part, const float* __restrict__ b1v,
    const float* __restrict__ w2, const float* __restrict__ b2,
    float* __restrict__ out)
{
  const int m = blockIdx.x;          // 0..127
  const int tid = threadIdx.x;
  float a0 = 0.f, a1 = 0.f;
  for (int j = tid; j < 1024; j += 256) {
    float s = b1v[j];
#pragma unroll
    for (int ks = 0; ks < 32; ++ks)
      s += part[((size_t)ks * 128 + m) * 1024 + j];
    s = fmaxf(s, 0.f);
    a0 = fmaf(s, w2[j], a0);
    a1 = fmaf(s, w2[1024 + j], a1);
  }
#pragma unroll
  for (int o = 32; o > 0; o >>= 1) {
    a0 += __shfl_down(a0, o);
    a1 += __shfl_down(a1, o);
  }
  __shared__ float r0[4], r1[4];
  const int wid = tid >> 6;
  if ((tid & 63) == 0) { r0[wid] = a0; r1[wid] = a1; }
  __syncthreads();
  if (tid == 0) {
    out[(size_t)m * 2 + 0] = r0[0] + r0[1] + r0[2] + r0[3] + b2[0];
    out[(size_t)m * 2 + 1] = r1[0] + r1[1] + r1[2] + r1[3] + b2[1];
  }
}

// ---------------------------------------------------------------------------
extern "C" void kernel_launch(void* const* d_in, const int* in_sizes, int n_in,
                              void* d_out, int out_size, void* d_ws, size_t ws_size,
                              hipStream_t stream)
{
  const float* image    = (const float*)d_in[0];
  const int*   question = (const int*)  d_in[1];
  const float* stem_w1  = (const float*)d_in[2];
  const float* stem_b1  = (const float*)d_in[3];
  const float* stem_w2  = (const float*)d_in[4];
  const float* stem_b2  = (const float*)d_in[5];
  const float* exp_w1   = (const float*)d_in[6];
  const float* exp_b1   = (const float*)d_in[7];
  const float* exp_w2   = (const float*)d_in[8];
  const float* exp_b2   = (const float*)d_in[9];
  const float* proj_w   = (const float*)d_in[10];
  const float* proj_b   = (const float*)d_in[11];
  const float* fc1_w    = (const float*)d_in[12];
  const float* fc1_b    = (const float*)d_in[13];
  const float* fc2_w    = (const float*)d_in[14];
  const float* fc2_b    = (const float*)d_in[15];
  float* out = (float*)d_out;

  char* base = (char*)d_ws;
  bf16_t* actA   = (bf16_t*)(base + 33554432);         // 33,554,432 B (NHWC 32x32)
  bf16_t* actH   = (bf16_t*)(base + 67108864);         //  8,388,608 B (NHWC 16x16)
  bf16_t* actT   = (bf16_t*)(base + 75497472);         //  8,388,608 B
  bf16_t* wT1    = (bf16_t*)(base + 83886080);         //  4,718,592 B (frag)
  bf16_t* wT2    = (bf16_t*)(base + 88604672);         //  4,718,592 B (frag)
  bf16_t* wTs2   = (bf16_t*)(base + 93323264);         //    294,912 B (frag)
  bf16_t* pwT    = (bf16_t*)(base + 93618176);         //    131,072 B (frag)
  // region0 reuse: f bf16, fc1 partials (32 slices)
  bf16_t* fbf  = (bf16_t*)base;                        //  8,388,608 B
  float*  part = (float*)(base + 8388608);             // 16,777,216 B (32x128x1024)

  // fused weight prep || stem1 (prep re-blocked for contiguous reads)
  prep_stem1_k<<<2376, 256, 0, stream>>>(exp_w1, exp_w2, stem_w2, proj_w,
                                         wT1, wT2, wTs2, pwT,
                                         image, stem_w1, stem_b1, actA);

  conv_stem2_k<<<1024, 256, 0, stream>>>(actA, wTs2, stem_b2, actH);

  // expert residual blocks, routing cols (3,4,6,7,5)
  const int cols[5] = {3, 4, 6, 7, 5};
  for (int i = 0; i < 5; ++i) {
    conv_exp_k<0><<<512, 256, 0, stream>>>(actH, wT1, exp_b1, question, cols[i],
                                           nullptr, actT);
    conv_exp_k<1><<<512, 256, 0, stream>>>(actT, wT2, exp_b2, question, cols[i],
                                           actH, actH);
  }

  // head
  proj_mfma_k<<<512, 256, 0, stream>>>(actH, pwT, proj_b, fbf);
  fc1_mfma_k<<<dim3(16, 32), 256, 0, stream>>>(fbf, fc1_w, part);
  fc_head_k<<<128, 256, 0, stream>>>(part, fc1_b, fc2_w, fc2_b, out);
}